// Round 2
// baseline (707.182 us; speedup 1.0000x reference)
//
#include <hip/hip_runtime.h>
#include <stdint.h>

#define F_DIM 321
#define O_DIM 720
#define I_DIM 512
#define B_DIM 32
#define G_F 8   // f's per block in the GEMM kernel

typedef __attribute__((ext_vector_type(8))) short short8;   // 8 bf16 = 4 VGPRs
typedef __attribute__((ext_vector_type(4))) float f32x4;
typedef __attribute__((ext_vector_type(4))) uint32_t u32x4;
typedef __attribute__((ext_vector_type(2))) uint32_t u32x2;

// Round-to-nearest-even fp32 -> bf16, packed pairwise into a dword.
__device__ __forceinline__ uint32_t rne_pack2(float lo, float hi) {
  uint32_t a = __builtin_bit_cast(uint32_t, lo);
  uint32_t b = __builtin_bit_cast(uint32_t, hi);
  a += 0x7FFFu + ((a >> 16) & 1u);
  b += 0x7FFFu + ((b >> 16) & 1u);
  return (a >> 16) | (b & 0xFFFF0000u);
}

// Kernel 1 (unchanged, verified): xn = x*inv + shift, bf16, A-frag-native:
// ws[f][iblk(64)][b(32)] = 16B = 8 consecutive i for that (b,f).
__global__ void __launch_bounds__(256) xn_pack_kernel(
    const float* __restrict__ x, const float* __restrict__ gamma,
    const float* __restrict__ beta, const float* __restrict__ rmean,
    const float* __restrict__ rvar, u32x4* __restrict__ ws) {
  __shared__ float tile[8 * F_DIM];
  const int iblk = blockIdx.x;  // 0..63
  const int b    = blockIdx.y;  // 0..31
  const float* src = x + ((size_t)b * I_DIM + (size_t)iblk * 8) * F_DIM;
  for (int idx = threadIdx.x; idx < 8 * F_DIM; idx += 256)
    tile[idx] = src[idx];
  __syncthreads();
  for (int f = threadIdx.x; f < F_DIM; f += 256) {
    float inv = gamma[f] * rsqrtf(rvar[f] + 1e-5f);
    float sh  = beta[f] - rmean[f] * inv;
    float v[8];
#pragma unroll
    for (int j = 0; j < 8; ++j) v[j] = fmaf(tile[j * F_DIM + f], inv, sh);
    u32x4 pk;
    pk.x = rne_pack2(v[0], v[1]);
    pk.y = rne_pack2(v[2], v[3]);
    pk.z = rne_pack2(v[4], v[5]);
    pk.w = rne_pack2(v[6], v[7]);
    ws[(size_t)f * 2048 + iblk * 32 + b] = pk;
  }
}

// Kernel 2 v4: OUTSTANDING-LOADS fix.
// Theory (R1..R3 synthesis): W-stream has been capped ~2-2.4 TB/s across
// three different access structures because hipcc packs eagerly -> only
// ~1-2 KB of W loads in flight per wave -> 16 waves * 1 KB / 900 cyc
// ~ 17 B/cyc/CU ~ 2.6 TB/s chip ceiling. Fix: hold all 16 loads of the
// NEXT f-tile in registers across the entire MFMA phase of the current
// tile (sched_barrier(0) fences stop hipcc reordering packs above MFMA),
// pack+write into the other half of a 64-KB LDS double buffer, ONE
// barrier per f-step. LDS caps occupancy at 2 blocks/CU (2 waves/EU ->
// VGPR budget 256, no spill risk for the ~160-reg live set); outstanding
// = 8 waves * 16 KB = 128 KB/CU, 14x what 6.3 TB/s needs.
__global__ void __launch_bounds__(256) linear_bn_kernel(
    const float* __restrict__ Wt, const float* __restrict__ bias,
    const u32x4* __restrict__ xn, float* __restrict__ out) {
  __shared__ u32x4 lds4[4096];  // 2 x 32 KB bf16 W-tiles (double buffer)
  char* ldsb = (char*)lds4;
  const int tid  = threadIdx.x;
  const int lane = tid & 63;
  const int wv   = tid >> 6;
  const int quad = lane >> 4;
  const int t16  = lane & 15;
  const int mtile = wv & 1;        // compute: b-half
  const int ntile = wv >> 1;       // compute: o-half

  // XCD-chunked bijective remap (m204 form; nwg=943=8*117+7): XCD k gets
  // ~118 consecutive work ids -> blocks sharing an f-group (same xn slice)
  // land on 1-2 XCDs instead of 8 -> xn L2-resident per XCD.
  const int d   = blockIdx.y * 23 + blockIdx.x;
  const int xcd = d & 7, idx = d >> 3;
  const int w   = (xcd < 7) ? xcd * 118 + idx : 826 + idx;
  const int bx  = w % 23;
  const int by  = w / 23;

  const int o0 = bx * 32;
  const int fb = by * G_F;
  const int nf = min(G_F, F_DIM - fb);   // tail group (fb=320) has nf=1
  const int oC = o0 + ntile * 16 + t16;  // compute column (guarded)

  // staging coords: thread owns float4-column sc of rows {2j+shi}
  const int sc  = tid & 127;   // i/4 within the row (0..127)
  const int shi = tid >> 7;    // row parity (0/1)

  f32x4 acc[G_F];
#pragma unroll
  for (int ff = 0; ff < G_F; ++ff) {
    float bv = 0.0f;
    if (ff < nf && oC < O_DIM) bv = bias[(size_t)(fb + ff) * O_DIM + oC];
    acc[ff] = (f32x4){bv, bv, bv, bv};
  }

  f32x4 raw[16];  // 64 VGPRs of in-flight W data (the whole point of v4)
  auto stage_issue = [&](int f) {
    const float* fbase = Wt + (size_t)f * (O_DIM * I_DIM) + sc * 4;
#pragma unroll
    for (int j = 0; j < 16; ++j) {
      // row clamp only bites for bx=22 (o 720..735 -> 719, L2-absorbed;
      // those B-frag rows feed only oC>=720 lanes, which are store-guarded)
      const int row = min(o0 + 2 * j + shi, O_DIM - 1);
      raw[j] = *(const f32x4*)(fbase + (size_t)row * I_DIM);
    }
  };
  auto pack_write = [&](int wOff) {
#pragma unroll
    for (int j = 0; j < 16; ++j) {   // dense swizzled b64 writes
      const int o = 2 * j + shi;
      const int byte = (((o * 128 + sc) * 8) ^ ((o & 7) << 4)) + wOff;
      u32x2 p;
      p.x = rne_pack2(raw[j].x, raw[j].y);
      p.y = rne_pack2(raw[j].z, raw[j].w);
      *(u32x2*)(ldsb + byte) = p;
    }
  };

  // Prologue: stage tile fb into buffer 0.
  stage_issue(fb);
  pack_write(0);
  __syncthreads();

#pragma unroll
  for (int ff = 0; ff < G_F; ++ff) {
    if (ff >= nf) break;               // nf is block-uniform: barrier-safe
    const int rOff = (ff & 1) ? 32768 : 0;
    const int wOff = rOff ^ 32768;
    if (ff + 1 < nf) stage_issue(fb + ff + 1);   // 16 loads go in flight
    __builtin_amdgcn_sched_barrier(0);           // keep them above MFMA
    const int f = fb + ff;
    const u32x4* xf = xn + (size_t)f * 2048 + mtile * 16 + t16;
    const int orow = ntile * 16 + t16;
    const int swz  = (t16 & 7) << 4;   // == (orow&7)<<4
#pragma unroll
    for (int kk = 0; kk < 16; ++kk) {
      u32x4 av = xf[(kk * 4 + quad) * 32];                      // A: L2-res
      u32x4 bv = *(const u32x4*)(
          ldsb + (((orow * 1024 + kk * 64 + quad * 16) ^ swz) + rOff));
      acc[ff] = __builtin_amdgcn_mfma_f32_16x16x32_bf16(
          __builtin_bit_cast(short8, av), __builtin_bit_cast(short8, bv),
          acc[ff], 0, 0, 0);
    }
    __builtin_amdgcn_sched_barrier(0);           // packs stay below MFMA
    if (ff + 1 < nf) pack_write(wOff);           // vmcnt drains AFTER compute
    __syncthreads();                             // one barrier per f-step
  }

  // Epilogue: C/D col = t16 (o), row = quad*4+r (b). ff-inner store order
  // gives 8 consecutive f-dwords per (b,o) -> L2 merges into 32-B runs.
  if (oC < O_DIM) {
#pragma unroll
    for (int r = 0; r < 4; ++r) {
      const int brow = mtile * 16 + quad * 4 + r;
      float* po = out + ((size_t)brow * O_DIM + oC) * F_DIM + fb;
#pragma unroll
      for (int ff = 0; ff < G_F; ++ff)
        if (ff < nf) po[ff] = acc[ff][r];
    }
  }
}

extern "C" void kernel_launch(void* const* d_in, const int* in_sizes, int n_in,
                              void* d_out, int out_size, void* d_ws, size_t ws_size,
                              hipStream_t stream) {
  const float* x     = (const float*)d_in[0];
  const float* W     = (const float*)d_in[1];
  const float* b     = (const float*)d_in[2];
  const float* gamma = (const float*)d_in[3];
  const float* beta  = (const float*)d_in[4];
  const float* rmean = (const float*)d_in[5];
  const float* rvar  = (const float*)d_in[6];
  u32x4* ws = (u32x4*)d_ws;  // 321*2048*16 B = 10.5 MB << ws_size

  xn_pack_kernel<<<dim3(64, 32), 256, 0, stream>>>(x, gamma, beta, rmean, rvar, ws);
  linear_bn_kernel<<<dim3(23, 41), 256, 0, stream>>>(W, b, ws, (float*)d_out);
}

// Round 3
// 672.879 us; speedup vs baseline: 1.0510x; 1.0510x over previous
//
#include <hip/hip_runtime.h>
#include <stdint.h>

#define F_DIM 321
#define O_DIM 720
#define I_DIM 512
#define B_DIM 32
#define G_F 8   // f's per block in the GEMM kernel

typedef __attribute__((ext_vector_type(8))) short short8;   // 8 bf16 = 4 VGPRs
typedef __attribute__((ext_vector_type(4))) float f32x4;
typedef __attribute__((ext_vector_type(4))) uint32_t u32x4;

// Round-to-nearest-even fp32 -> bf16, packed pairwise into a dword.
__device__ __forceinline__ uint32_t rne_pack2(float lo, float hi) {
  uint32_t a = __builtin_bit_cast(uint32_t, lo);
  uint32_t b = __builtin_bit_cast(uint32_t, hi);
  a += 0x7FFFu + ((a >> 16) & 1u);
  b += 0x7FFFu + ((b >> 16) & 1u);
  return (a >> 16) | (b & 0xFFFF0000u);
}

// global -> LDS direct DMA, 16 B per lane. LDS dest is wave-uniform;
// HW scatters lane L to ldsbase + 16*L. C-style casts perform the
// generic->AS1/AS3 addrspacecasts.
__device__ __forceinline__ void gload_lds16(const void* g, void* l) {
  __builtin_amdgcn_global_load_lds(
      (const __attribute__((address_space(1))) uint32_t*)g,
      (__attribute__((address_space(3))) uint32_t*)l, 16, 0, 0);
}

// Kernel 1 (unchanged, verified): xn = x*inv + shift, bf16, A-frag-native:
// ws[f][iblk(64)][b(32)] = 16B = 8 consecutive i for that (b,f).
__global__ void __launch_bounds__(256) xn_pack_kernel(
    const float* __restrict__ x, const float* __restrict__ gamma,
    const float* __restrict__ beta, const float* __restrict__ rmean,
    const float* __restrict__ rvar, u32x4* __restrict__ ws) {
  __shared__ float tile[8 * F_DIM];
  const int iblk = blockIdx.x;  // 0..63
  const int b    = blockIdx.y;  // 0..31
  const float* src = x + ((size_t)b * I_DIM + (size_t)iblk * 8) * F_DIM;
  for (int idx = threadIdx.x; idx < 8 * F_DIM; idx += 256)
    tile[idx] = src[idx];
  __syncthreads();
  for (int f = threadIdx.x; f < F_DIM; f += 256) {
    float inv = gamma[f] * rsqrtf(rvar[f] + 1e-5f);
    float sh  = beta[f] - rmean[f] * inv;
    float v[8];
#pragma unroll
    for (int j = 0; j < 8; ++j) v[j] = fmaf(tile[j * F_DIM + f], inv, sh);
    u32x4 pk;
    pk.x = rne_pack2(v[0], v[1]);
    pk.y = rne_pack2(v[2], v[3]);
    pk.z = rne_pack2(v[4], v[5]);
    pk.w = rne_pack2(v[6], v[7]);
    ws[(size_t)f * 2048 + iblk * 32 + b] = pk;
  }
}

// Kernel 2 v5: m97-structure streaming. W staged fp32 via global_load_lds
// (no VGPR round-trip, no packs -> wave's vmcnt is NOT entangled with the
// A-loads; the only drain is the barrier, covered by the other block on
// the CU). fp32->bf16 conversion moves into the fragment build (~200 VALU
// cyc/step, ~3% of the 6400-cyc memory budget).
//
// Swizzle (m173 pattern: gl_lds writes LINEARLY, so swizzle the SOURCE):
//   LDS[b] = Wtile[b ^ s],  s = ((b>>11)&7)<<4   (b>>11 = o row, 2 KB/row)
//   - staging instr k (1 KB, o = k>>1 uniform): gaddr = tile + (k*1024 +
//     (16L ^ s_k)) -> dense 1-KB burst, 16-B chunks permuted in-line.
//   - frag read at (o*2048 + kk*128 + quad*32 + h*16) ^ ((o&7)<<4):
//     slot class = (quad<<1)^(t16&7) -> exactly 8 lanes per 16-B slot
//     class = uniform over banks = optimal for b128.
__global__ void __launch_bounds__(256, 2) linear_bn_kernel(
    const float* __restrict__ Wt, const float* __restrict__ bias,
    const u32x4* __restrict__ xn, float* __restrict__ out) {
  __shared__ u32x4 lds4[4096];  // 64 KB: 32 o x 512 i fp32 tile
  char* ldsb = (char*)lds4;
  const int tid  = threadIdx.x;
  const int lane = tid & 63;
  const int wv   = tid >> 6;
  const int quad = lane >> 4;
  const int t16  = lane & 15;
  const int mtile = wv & 1;        // compute: b-half
  const int ntile = wv >> 1;       // compute: o-half

  // XCD-chunked bijective remap (m204 form; nwg=943=8*117+7): blocks
  // sharing an f-group (same xn slice) land on 1-2 XCDs -> xn L2-resident.
  const int d   = blockIdx.y * 23 + blockIdx.x;
  const int xcd = d & 7, idx = d >> 3;
  const int w   = (xcd < 7) ? xcd * 118 + idx : 826 + idx;
  const int bx  = w % 23;
  const int by  = w / 23;

  const int o0 = bx * 32;
  const int fb = by * G_F;
  const int nf = min(G_F, F_DIM - fb);   // tail group (fb=320) has nf=1
  const int oC = o0 + ntile * 16 + t16;  // compute column (guarded)

  f32x4 acc[G_F];
#pragma unroll
  for (int ff = 0; ff < G_F; ++ff) {
    float bv = 0.0f;
    if (ff < nf && oC < O_DIM) bv = bias[(size_t)(fb + ff) * O_DIM + oC];
    acc[ff] = (f32x4){bv, bv, bv, bv};
  }

  // Staging: 16 gl_lds DMA instructions per wave = 16 KB; 4 waves = 64 KB.
  auto stage = [&](int f) {
    const char* fbase = (const char*)Wt + (size_t)f * (O_DIM * I_DIM * 4);
#pragma unroll
    for (int j = 0; j < 16; ++j) {
      const int k = wv * 16 + j;
      const int o = min(o0 + (k >> 1), O_DIM - 1);  // bx=22 clamp: rows
      const int s = ((k >> 1) & 7) << 4;            // >=720 store-guarded
      const char* g = fbase + (size_t)o * 2048 + (k & 1) * 1024
                      + ((16 * lane) ^ s);
      gload_lds16(g, ldsb + k * 1024);
    }
  };

  const int orow = ntile * 16 + t16;
  const int swz  = (t16 & 7) << 4;   // == (orow&7)<<4

#pragma unroll
  for (int ff = 0; ff < G_F; ++ff) {
    if (ff >= nf) break;               // nf is block-uniform: barrier-safe
    if (ff) __syncthreads();           // prev step's LDS reads complete
    stage(fb + ff);                    // 16 DMAs go in flight
    const int f = fb + ff;
    const u32x4* xf = xn + (size_t)f * 2048 + mtile * 16 + t16;
    u32x4 av[16];                      // A-frags to regs while DMA flies
#pragma unroll
    for (int kk = 0; kk < 16; ++kk) av[kk] = xf[(kk * 4 + quad) * 32];
    __syncthreads();                   // vmcnt(0) drain: tile + av ready
#pragma unroll
    for (int kk = 0; kk < 16; ++kk) {
      const int lin = orow * 2048 + kk * 128 + quad * 32;
      f32x4 w0 = *(const f32x4*)(ldsb + ((lin) ^ swz));
      f32x4 w1 = *(const f32x4*)(ldsb + ((lin + 16) ^ swz));
      u32x4 bv;
      bv.x = rne_pack2(w0.x, w0.y);
      bv.y = rne_pack2(w0.z, w0.w);
      bv.z = rne_pack2(w1.x, w1.y);
      bv.w = rne_pack2(w1.z, w1.w);
      acc[ff] = __builtin_amdgcn_mfma_f32_16x16x32_bf16(
          __builtin_bit_cast(short8, av[kk]), __builtin_bit_cast(short8, bv),
          acc[ff], 0, 0, 0);
    }
  }

  // Epilogue: C/D col = t16 (o), row = quad*4+r (b). ff-inner store order
  // gives 8 consecutive f-dwords per (b,o) -> L2 merges into 32-B runs.
  if (oC < O_DIM) {
#pragma unroll
    for (int r = 0; r < 4; ++r) {
      const int brow = mtile * 16 + quad * 4 + r;
      float* po = out + ((size_t)brow * O_DIM + oC) * F_DIM + fb;
#pragma unroll
      for (int ff = 0; ff < G_F; ++ff)
        if (ff < nf) po[ff] = acc[ff][r];
    }
  }
}

extern "C" void kernel_launch(void* const* d_in, const int* in_sizes, int n_in,
                              void* d_out, int out_size, void* d_ws, size_t ws_size,
                              hipStream_t stream) {
  const float* x     = (const float*)d_in[0];
  const float* W     = (const float*)d_in[1];
  const float* b     = (const float*)d_in[2];
  const float* gamma = (const float*)d_in[3];
  const float* beta  = (const float*)d_in[4];
  const float* rmean = (const float*)d_in[5];
  const float* rvar  = (const float*)d_in[6];
  u32x4* ws = (u32x4*)d_ws;  // 321*2048*16 B = 10.5 MB << ws_size

  xn_pack_kernel<<<dim3(64, 32), 256, 0, stream>>>(x, gamma, beta, rmean, rvar, ws);
  linear_bn_kernel<<<dim3(23, 41), 256, 0, stream>>>(W, b, ws, (float*)d_out);
}